// Round 5
// baseline (865.983 us; speedup 1.0000x reference)
//
#include <hip/hip_runtime.h>

// Actor_attf_single — MI355X (gfx950)
// R14: bigger batches + fully-unrolled passes. Ledger:
//   R8  329us: 2-entity batch, VGPR 76, no spills
//   R9  352us: role-split TLP — regressed; TLP not the limiter
//   R10 1445us: LDS weights -> VGPR 256 + massive scratch spills
//   R11 289us: batch 3/4, VGPR squeezed to 64 -> ~20MB spill evictions
//   R13 291us: VGPR cap 256 -> allocator chose 80, ~5MB spill evictions
//       remain, occupancy 34->28 -> spill savings == occupancy loss. Wash.
// Model: wall 696K cyc/SIMD vs ~208K pure-math issue demand; overhead =
// per-pass weight re-stream (s_load burst + lgkmcnt drain at each pass top)
// + residual spill code. R14 attacks the weight stream:
//   - "other": 3 passes of 5 entities (was 5 passes of 3)
//   - "food":  3 passes {6,5,5}  (was 4 passes of 4)
//   - passes written as EXPLICIT template calls (no #pragma unroll 1), so
//     the compiler can prefetch pass k+1's s_loads under pass k's FMA tail
// Per-entity math + softmax update order bitwise-identical to R8/R11/R13
// (absmax must stay 0.00390625). Weights stay on the s_load/SGPR path.
// Success criterion: WRITE_SIZE <= ~4MB (no new spills) with VGPR 130-165.

#define LN_EPS 1e-5f

struct Weights {
  const float* __restrict__ en_W1; const float* __restrict__ en_b1;
  const float* __restrict__ en_W2; const float* __restrict__ en_b2;
  const float* __restrict__ oa_W1; const float* __restrict__ oa_b1;
  const float* __restrict__ oa_W2; const float* __restrict__ oa_b2;
  const float* __restrict__ go_W1; const float* __restrict__ go_b1;
  const float* __restrict__ go_W2; const float* __restrict__ go_b2;
  const float* __restrict__ oa_g;  const float* __restrict__ oa_b;
  const float* __restrict__ go_g;  const float* __restrict__ go_b;
  const float* __restrict__ a_W1;  const float* __restrict__ a_b1;
  const float* __restrict__ a_W2;  const float* __restrict__ a_b2;
  const float* __restrict__ a_W3;  const float* __restrict__ a_b3;
};

__device__ __forceinline__ float2 ld2(const float* __restrict__ p) {
  return *reinterpret_cast<const float2*>(p);
}

// ---- one batch of NE "other" entities starting at k0 (compile-time) ------
template<int NE>
__device__ __forceinline__ void oa_batch(const float* __restrict__ srow, int k0,
                                         const Weights& W,
                                         const float (&self_out)[16],
                                         float (&acc)[16], float& m, float& l) {
  float2 i01[NE], i23[NE];
#pragma unroll
  for (int e = 0; e < NE; ++e) {
    i01[e] = ld2(srow + 4  + 2*(k0 + e));
    i23[e] = ld2(srow + 34 + 2*(k0 + e));
  }
  float enc[NE][16];
#pragma unroll
  for (int d = 0; d < 16; ++d) {
    float b2 = W.oa_b2[d];
#pragma unroll
    for (int e = 0; e < NE; ++e) enc[e][d] = b2;
  }
#pragma unroll
  for (int j = 0; j < 32; ++j) {
    float w0 = W.oa_W1[ 0 + j], w1 = W.oa_W1[32 + j];
    float w2 = W.oa_W1[64 + j], w3 = W.oa_W1[96 + j];
    float b1 = W.oa_b1[j];
    float h[NE];
#pragma unroll
    for (int e = 0; e < NE; ++e) {
      float t = fmaf(i01[e].x, w0, b1);
      t = fmaf(i01[e].y, w1, t);
      t = fmaf(i23[e].x, w2, t);
      t = fmaf(i23[e].y, w3, t);
      h[e] = fmaxf(t, 0.f);
    }
#pragma unroll
    for (int d = 0; d < 16; ++d) {
      float w = W.oa_W2[j*16 + d];
#pragma unroll
      for (int e = 0; e < NE; ++e) enc[e][d] = fmaf(h[e], w, enc[e][d]);
    }
  }
  // per-entity epilogue, strictly in entity order (bitwise == R8)
#pragma unroll
  for (int e = 0; e < NE; ++e) {
    float s = 0.f;
#pragma unroll
    for (int d = 0; d < 16; ++d) {
      enc[e][d] = fmaxf(enc[e][d], 0.f);
      s = fmaf(self_out[d], enc[e][d], s);
    }
    s *= 0.25f;
    float mn = fmaxf(m, s);
    float alpha = __expf(m - mn), w = __expf(s - mn);
    l = fmaf(l, alpha, w);
#pragma unroll
    for (int d = 0; d < 16; ++d) acc[d] = fmaf(acc[d], alpha, w * enc[e][d]);
    m = mn;
  }
}

// ---- one batch of NE "food" entities starting at k0 (compile-time) -------
template<int NE>
__device__ __forceinline__ void go_batch(const float* __restrict__ srow, int k0,
                                         const Weights& W,
                                         const float (&self_out)[16],
                                         float (&acc)[16], float& m, float& l) {
  float2 fi[NE];
#pragma unroll
  for (int e = 0; e < NE; ++e) fi[e] = ld2(srow + 64 + 2*(k0 + e));
  float enc[NE][16];
#pragma unroll
  for (int d = 0; d < 16; ++d) {
    float b2 = W.go_b2[d];
#pragma unroll
    for (int e = 0; e < NE; ++e) enc[e][d] = b2;
  }
#pragma unroll
  for (int j = 0; j < 32; ++j) {
    float w0 = W.go_W1[0 + j], w1 = W.go_W1[32 + j];
    float b1 = W.go_b1[j];
    float h[NE];
#pragma unroll
    for (int e = 0; e < NE; ++e) {
      float t = fmaf(fi[e].x, w0, b1);
      t = fmaf(fi[e].y, w1, t);
      h[e] = fmaxf(t, 0.f);
    }
#pragma unroll
    for (int d = 0; d < 16; ++d) {
      float w = W.go_W2[j*16 + d];
#pragma unroll
      for (int e = 0; e < NE; ++e) enc[e][d] = fmaf(h[e], w, enc[e][d]);
    }
  }
  // per-entity epilogue, strictly in entity order (bitwise == R8)
#pragma unroll
  for (int e = 0; e < NE; ++e) {
    float s = 0.f;
#pragma unroll
    for (int d = 0; d < 16; ++d) {
      enc[e][d] = fmaxf(enc[e][d], 0.f);
      s = fmaf(self_out[d], enc[e][d], s);
    }
    s *= 0.25f;
    float mn = fmaxf(m, s);
    float alpha = __expf(m - mn), w = __expf(s - mn);
    l = fmaf(l, alpha, w);
#pragma unroll
    for (int d = 0; d < 16; ++d) acc[d] = fmaf(acc[d], alpha, w * enc[e][d]);
    m = mn;
  }
}

__global__ __launch_bounds__(256, 2)
void actor_fwd(const float* __restrict__ s_input, Weights W,
               float* __restrict__ out, int bsz) {
  const int lane = threadIdx.x & 63;
  const int wv   = threadIdx.x >> 6;        // 0..3, independent waves
  int row = blockIdx.x * 256 + wv * 64 + lane;
  row = min(row, bsz - 1);
  const float* __restrict__ srow = s_input + (size_t)row * 96;

  // ---------------- self encoder: fused 4 -> 32 -> 16, relu ----------------
  float self_out[16];
  {
    float2 p01 = ld2(srow + 0);
    float2 p23 = ld2(srow + 2);
#pragma unroll
    for (int d = 0; d < 16; ++d) self_out[d] = W.en_b2[d];
#pragma unroll
    for (int j = 0; j < 32; ++j) {
      float h = W.en_b1[j];
      h = fmaf(p01.x, W.en_W1[ 0 + j], h);
      h = fmaf(p01.y, W.en_W1[32 + j], h);
      h = fmaf(p23.x, W.en_W1[64 + j], h);
      h = fmaf(p23.y, W.en_W1[96 + j], h);
      h = fmaxf(h, 0.f);
#pragma unroll
      for (int d = 0; d < 16; ++d)
        self_out[d] = fmaf(h, W.en_W2[j*16 + d], self_out[d]);
    }
#pragma unroll
    for (int d = 0; d < 16; ++d) self_out[d] = fmaxf(self_out[d], 0.f);
  }

  // ------- other agents: 15 entities = 3 passes of 5 ---------------------
  float other_pool[16];
  {
    float m = -3.0e38f, l = 0.f, acc[16];
#pragma unroll
    for (int d = 0; d < 16; ++d) acc[d] = 0.f;

    oa_batch<5>(srow,  0, W, self_out, acc, m, l);
    oa_batch<5>(srow,  5, W, self_out, acc, m, l);
    oa_batch<5>(srow, 10, W, self_out, acc, m, l);

    float inv = 1.f / l;
    float mu = 0.f;
#pragma unroll
    for (int d = 0; d < 16; ++d) { acc[d] *= inv; mu += acc[d]; }
    mu *= (1.f / 16.f);
    float var = 0.f;
#pragma unroll
    for (int d = 0; d < 16; ++d) { float x = acc[d] - mu; var = fmaf(x, x, var); }
    var *= (1.f / 16.f);
    float rstd = rsqrtf(var + LN_EPS);
#pragma unroll
    for (int d = 0; d < 16; ++d)
      other_pool[d] = fmaxf(fmaf((acc[d] - mu) * rstd, W.oa_g[d], W.oa_b[d]), 0.f);
  }

  // ------- food: 16 entities = 3 passes {6,5,5} --------------------------
  float food_pool[16];
  {
    float m = -3.0e38f, l = 0.f, acc[16];
#pragma unroll
    for (int d = 0; d < 16; ++d) acc[d] = 0.f;

    go_batch<6>(srow,  0, W, self_out, acc, m, l);
    go_batch<5>(srow,  6, W, self_out, acc, m, l);
    go_batch<5>(srow, 11, W, self_out, acc, m, l);

    float inv = 1.f / l;
    float mu = 0.f;
#pragma unroll
    for (int d = 0; d < 16; ++d) { acc[d] *= inv; mu += acc[d]; }
    mu *= (1.f / 16.f);
    float var = 0.f;
#pragma unroll
    for (int d = 0; d < 16; ++d) { float x = acc[d] - mu; var = fmaf(x, x, var); }
    var *= (1.f / 16.f);
    float rstd = rsqrtf(var + LN_EPS);
#pragma unroll
    for (int d = 0; d < 16; ++d)
      food_pool[d] = fmaxf(fmaf((acc[d] - mu) * rstd, W.go_g[d], W.go_b[d]), 0.f);
  }

  // ------- action head: 48 -> 32 -> 32 -> 2 ------------------------------
  float h1[32];
#pragma unroll
  for (int j = 0; j < 32; ++j) h1[j] = W.a_b1[j];
#pragma unroll
  for (int c = 0; c < 16; ++c) {
    float v = self_out[c];
#pragma unroll
    for (int j = 0; j < 32; ++j) h1[j] = fmaf(v, W.a_W1[c*32 + j], h1[j]);
  }
#pragma unroll
  for (int c = 0; c < 16; ++c) {
    float v = food_pool[c];
#pragma unroll
    for (int j = 0; j < 32; ++j) h1[j] = fmaf(v, W.a_W1[(16 + c)*32 + j], h1[j]);
  }
#pragma unroll
  for (int c = 0; c < 16; ++c) {
    float v = other_pool[c];
#pragma unroll
    for (int j = 0; j < 32; ++j) h1[j] = fmaf(v, W.a_W1[(32 + c)*32 + j], h1[j]);
  }
#pragma unroll
  for (int j = 0; j < 32; ++j) h1[j] = fmaxf(h1[j], 0.01f * h1[j]);   // leaky

  float h2[32];
#pragma unroll
  for (int j = 0; j < 32; ++j) h2[j] = W.a_b2[j];
#pragma unroll
  for (int c = 0; c < 32; ++c) {
    float v = h1[c];
#pragma unroll
    for (int j = 0; j < 32; ++j) h2[j] = fmaf(v, W.a_W2[c*32 + j], h2[j]);
  }
#pragma unroll
  for (int j = 0; j < 32; ++j) h2[j] = fmaxf(h2[j], 0.01f * h2[j]);

  float o0 = W.a_b3[0], o1 = W.a_b3[1];
#pragma unroll
  for (int c = 0; c < 32; ++c) {
    o0 = fmaf(h2[c], W.a_W3[c*2 + 0], o0);
    o1 = fmaf(h2[c], W.a_W3[c*2 + 1], o1);
  }
  o0 = tanhf(o0);
  o1 = tanhf(o1);

  reinterpret_cast<float2*>(out)[row] = make_float2(o0, o1);
}

extern "C" void kernel_launch(void* const* d_in, const int* in_sizes, int n_in,
                              void* d_out, int out_size, void* d_ws, size_t ws_size,
                              hipStream_t stream) {
  const float* s_input = (const float*)d_in[0];
  Weights W;
  W.en_W1 = (const float*)d_in[1];  W.en_b1 = (const float*)d_in[2];
  W.en_W2 = (const float*)d_in[3];  W.en_b2 = (const float*)d_in[4];
  W.oa_W1 = (const float*)d_in[5];  W.oa_b1 = (const float*)d_in[6];
  W.oa_W2 = (const float*)d_in[7];  W.oa_b2 = (const float*)d_in[8];
  W.go_W1 = (const float*)d_in[9];  W.go_b1 = (const float*)d_in[10];
  W.go_W2 = (const float*)d_in[11]; W.go_b2 = (const float*)d_in[12];
  W.oa_g  = (const float*)d_in[13]; W.oa_b  = (const float*)d_in[14];
  W.go_g  = (const float*)d_in[15]; W.go_b  = (const float*)d_in[16];
  W.a_W1  = (const float*)d_in[17]; W.a_b1  = (const float*)d_in[18];
  W.a_W2  = (const float*)d_in[19]; W.a_b2  = (const float*)d_in[20];
  W.a_W3  = (const float*)d_in[21]; W.a_b3  = (const float*)d_in[22];

  const int bsz = in_sizes[0] / 96;          // 262144
  const int blocks = (bsz + 255) / 256;      // 256 rows per block, 4 waves
  actor_fwd<<<blocks, 256, 0, stream>>>(s_input, W, (float*)d_out, bsz);
}

// Round 7
// 315.851 us; speedup vs baseline: 2.7417x; 2.7417x over previous
//
#include <hip/hip_runtime.h>
#include <stdint.h>

// Actor_attf_single — MI355X (gfx950)
// R16 = R15 with the compile fix (cvt_pkrtz returns __fp16 vector ->
// bit_cast to our _Float16-based h2; fdot2 already type-checked OK).
// R15 theory under test: fp32 structures all land at wall*VALUBusy ~=
// 552-582K cyc/SIMD (R8/R11/R13) => VALU-issue-bound at fixed instruction
// budget; v_dot2_f32_f16 halves the MAC instruction count.
//   - prep kernel packs all weights as half2 pairs (RNE) along the
//     contraction dim into d_ws (2240 dwords); same-stream launch
//   - activations packed via v_cvt_pkrtz_f16_f32 (RTZ)
//   - biases/accumulators/score-dot/softmax/LN/leaky/tanh all stay fp32
//   - structure otherwise R13 verbatim: batch 3 (other) / 4 (food),
//     launch_bounds(256,2), scalar weights on the s_load/SGPR path
// Numerics gamble (pre-committed): absmax expected 0.004-0.012; if FAIL,
// next round reverts to R13 fp32.

#define LN_EPS 1e-5f

typedef _Float16 h2 __attribute__((ext_vector_type(2)));

struct Weights {
  const float* __restrict__ en_W1; const float* __restrict__ en_b1;
  const float* __restrict__ en_W2; const float* __restrict__ en_b2;
  const float* __restrict__ oa_W1; const float* __restrict__ oa_b1;
  const float* __restrict__ oa_W2; const float* __restrict__ oa_b2;
  const float* __restrict__ go_W1; const float* __restrict__ go_b1;
  const float* __restrict__ go_W2; const float* __restrict__ go_b2;
  const float* __restrict__ oa_g;  const float* __restrict__ oa_b;
  const float* __restrict__ go_g;  const float* __restrict__ go_b;
  const float* __restrict__ a_W1;  const float* __restrict__ a_b1;
  const float* __restrict__ a_W2;  const float* __restrict__ a_b2;
  const float* __restrict__ a_W3;  const float* __restrict__ a_b3;
};

// workspace layout (uint32 = packed half2 units)
constexpr int P_EN_W1 = 0;     //  64: [j]=rows(0,1), [32+j]=rows(2,3)
constexpr int P_EN_W2 = 64;    // 256: [jp*16+d] = (W2[2jp][d], W2[2jp+1][d])
constexpr int P_OA_W1 = 320;   //  64
constexpr int P_OA_W2 = 384;   // 256
constexpr int P_GO_W1 = 640;   //  32: [j] = (W1[0][j], W1[1][j])
constexpr int P_GO_W2 = 672;   // 256
constexpr int P_A_W1  = 928;   // 768: [cp*32+j] = (W1[2cp][j], W1[2cp+1][j])
constexpr int P_A_W2  = 1696;  // 512
constexpr int P_A_W3  = 2208;  //  32: [cp*2+o] = (W3[2cp][o], W3[2cp+1][o])
// total 2240 u32 = 8960 bytes

__device__ __forceinline__ float2 ld2(const float* __restrict__ p) {
  return *reinterpret_cast<const float2*>(p);
}
__device__ __forceinline__ uint32_t pack_rne(float a, float b) {
  h2 v; v.x = (_Float16)a; v.y = (_Float16)b;
  return __builtin_bit_cast(uint32_t, v);
}
__device__ __forceinline__ h2 asH2(uint32_t u) { return __builtin_bit_cast(h2, u); }
__device__ __forceinline__ float fdot2(h2 a, h2 b, float c) {
  return __builtin_amdgcn_fdot2(a, b, c, false);
}
__device__ __forceinline__ h2 pkrtz(float a, float b) {
  return __builtin_bit_cast(h2, __builtin_amdgcn_cvt_pkrtz(a, b));
}

// ---- prep: fp32 weights -> packed half2 in workspace ---------------------
__global__ void prep_weights(Weights W, uint32_t* __restrict__ ws) {
  const int t = threadIdx.x;
  if (t < 32) {
    ws[P_EN_W1 + t]      = pack_rne(W.en_W1[t],      W.en_W1[32 + t]);
    ws[P_EN_W1 + 32 + t] = pack_rne(W.en_W1[64 + t], W.en_W1[96 + t]);
    ws[P_OA_W1 + t]      = pack_rne(W.oa_W1[t],      W.oa_W1[32 + t]);
    ws[P_OA_W1 + 32 + t] = pack_rne(W.oa_W1[64 + t], W.oa_W1[96 + t]);
    ws[P_GO_W1 + t]      = pack_rne(W.go_W1[t],      W.go_W1[32 + t]);
  }
  {
    int jp = t >> 4, d = t & 15;
    ws[P_EN_W2 + t] = pack_rne(W.en_W2[(2*jp)*16 + d], W.en_W2[(2*jp+1)*16 + d]);
    ws[P_OA_W2 + t] = pack_rne(W.oa_W2[(2*jp)*16 + d], W.oa_W2[(2*jp+1)*16 + d]);
    ws[P_GO_W2 + t] = pack_rne(W.go_W2[(2*jp)*16 + d], W.go_W2[(2*jp+1)*16 + d]);
  }
  for (int i = t; i < 768; i += 256) {
    int cp = i >> 5, j = i & 31;
    ws[P_A_W1 + i] = pack_rne(W.a_W1[(2*cp)*32 + j], W.a_W1[(2*cp+1)*32 + j]);
  }
  for (int i = t; i < 512; i += 256) {
    int cp = i >> 5, j = i & 31;
    ws[P_A_W2 + i] = pack_rne(W.a_W2[(2*cp)*32 + j], W.a_W2[(2*cp+1)*32 + j]);
  }
  if (t < 32) {
    int cp = t >> 1, o = t & 1;
    ws[P_A_W3 + t] = pack_rne(W.a_W3[(2*cp)*2 + o], W.a_W3[(2*cp+1)*2 + o]);
  }
}

// ---- one batch of NE "other" entities starting at k0 ---------------------
template<int NE>
__device__ __forceinline__ void oa_batch(const float* __restrict__ srow, int k0,
                                         const Weights& W,
                                         const uint32_t* __restrict__ wsu,
                                         const float (&self_out)[16],
                                         float (&acc)[16], float& m, float& l) {
  h2 a01[NE], a23[NE];
#pragma unroll
  for (int e = 0; e < NE; ++e) {
    float2 x = ld2(srow + 4  + 2*(k0 + e));
    float2 y = ld2(srow + 34 + 2*(k0 + e));
    a01[e] = pkrtz(x.x, x.y);
    a23[e] = pkrtz(y.x, y.y);
  }
  float enc[NE][16];
#pragma unroll
  for (int d = 0; d < 16; ++d) {
    float b2 = W.oa_b2[d];
#pragma unroll
    for (int e = 0; e < NE; ++e) enc[e][d] = b2;
  }
#pragma unroll
  for (int jp = 0; jp < 16; ++jp) {
    const int j0 = 2*jp, j1 = 2*jp + 1;
    const float b10 = W.oa_b1[j0], b11 = W.oa_b1[j1];
    const h2 wA0 = asH2(wsu[P_OA_W1 + j0]), wB0 = asH2(wsu[P_OA_W1 + 32 + j0]);
    const h2 wA1 = asH2(wsu[P_OA_W1 + j1]), wB1 = asH2(wsu[P_OA_W1 + 32 + j1]);
    h2 hh[NE];
#pragma unroll
    for (int e = 0; e < NE; ++e) {
      float h0 = fmaxf(fdot2(a01[e], wA0, fdot2(a23[e], wB0, b10)), 0.f);
      float h1 = fmaxf(fdot2(a01[e], wA1, fdot2(a23[e], wB1, b11)), 0.f);
      hh[e] = pkrtz(h0, h1);
    }
#pragma unroll
    for (int d = 0; d < 16; ++d) {
      const h2 wd = asH2(wsu[P_OA_W2 + jp*16 + d]);
#pragma unroll
      for (int e = 0; e < NE; ++e) enc[e][d] = fdot2(hh[e], wd, enc[e][d]);
    }
  }
  // per-entity epilogue, strictly in entity order (fp32)
#pragma unroll
  for (int e = 0; e < NE; ++e) {
    float s = 0.f;
#pragma unroll
    for (int d = 0; d < 16; ++d) {
      enc[e][d] = fmaxf(enc[e][d], 0.f);
      s = fmaf(self_out[d], enc[e][d], s);
    }
    s *= 0.25f;
    float mn = fmaxf(m, s);
    float alpha = __expf(m - mn), w = __expf(s - mn);
    l = fmaf(l, alpha, w);
#pragma unroll
    for (int d = 0; d < 16; ++d) acc[d] = fmaf(acc[d], alpha, w * enc[e][d]);
    m = mn;
  }
}

// ---- one batch of NE "food" entities starting at k0 ----------------------
template<int NE>
__device__ __forceinline__ void go_batch(const float* __restrict__ srow, int k0,
                                         const Weights& W,
                                         const uint32_t* __restrict__ wsu,
                                         const float (&self_out)[16],
                                         float (&acc)[16], float& m, float& l) {
  h2 ah[NE];
#pragma unroll
  for (int e = 0; e < NE; ++e) {
    float2 x = ld2(srow + 64 + 2*(k0 + e));
    ah[e] = pkrtz(x.x, x.y);
  }
  float enc[NE][16];
#pragma unroll
  for (int d = 0; d < 16; ++d) {
    float b2 = W.go_b2[d];
#pragma unroll
    for (int e = 0; e < NE; ++e) enc[e][d] = b2;
  }
#pragma unroll
  for (int jp = 0; jp < 16; ++jp) {
    const int j0 = 2*jp, j1 = 2*jp + 1;
    const float b10 = W.go_b1[j0], b11 = W.go_b1[j1];
    const h2 w0 = asH2(wsu[P_GO_W1 + j0]);
    const h2 w1 = asH2(wsu[P_GO_W1 + j1]);
    h2 hh[NE];
#pragma unroll
    for (int e = 0; e < NE; ++e) {
      float h0 = fmaxf(fdot2(ah[e], w0, b10), 0.f);
      float h1 = fmaxf(fdot2(ah[e], w1, b11), 0.f);
      hh[e] = pkrtz(h0, h1);
    }
#pragma unroll
    for (int d = 0; d < 16; ++d) {
      const h2 wd = asH2(wsu[P_GO_W2 + jp*16 + d]);
#pragma unroll
      for (int e = 0; e < NE; ++e) enc[e][d] = fdot2(hh[e], wd, enc[e][d]);
    }
  }
  // per-entity epilogue, strictly in entity order (fp32)
#pragma unroll
  for (int e = 0; e < NE; ++e) {
    float s = 0.f;
#pragma unroll
    for (int d = 0; d < 16; ++d) {
      enc[e][d] = fmaxf(enc[e][d], 0.f);
      s = fmaf(self_out[d], enc[e][d], s);
    }
    s *= 0.25f;
    float mn = fmaxf(m, s);
    float alpha = __expf(m - mn), w = __expf(s - mn);
    l = fmaf(l, alpha, w);
#pragma unroll
    for (int d = 0; d < 16; ++d) acc[d] = fmaf(acc[d], alpha, w * enc[e][d]);
    m = mn;
  }
}

__global__ __launch_bounds__(256, 2)
void actor_fwd(const float* __restrict__ s_input, Weights W,
               const uint32_t* __restrict__ wsu,
               float* __restrict__ out, int bsz) {
  const int lane = threadIdx.x & 63;
  const int wv   = threadIdx.x >> 6;
  int row = blockIdx.x * 256 + wv * 64 + lane;
  row = min(row, bsz - 1);
  const float* __restrict__ srow = s_input + (size_t)row * 96;

  // ---------------- self encoder: fused 4 -> 32 -> 16, relu ----------------
  float self_out[16];
  {
    float2 p01 = ld2(srow + 0);
    float2 p23 = ld2(srow + 2);
    h2 a01 = pkrtz(p01.x, p01.y);
    h2 a23 = pkrtz(p23.x, p23.y);
#pragma unroll
    for (int d = 0; d < 16; ++d) self_out[d] = W.en_b2[d];
#pragma unroll
    for (int jp = 0; jp < 16; ++jp) {
      const int j0 = 2*jp, j1 = 2*jp + 1;
      float h0 = fmaxf(fdot2(a01, asH2(wsu[P_EN_W1 + j0]),
                     fdot2(a23, asH2(wsu[P_EN_W1 + 32 + j0]), W.en_b1[j0])), 0.f);
      float h1 = fmaxf(fdot2(a01, asH2(wsu[P_EN_W1 + j1]),
                     fdot2(a23, asH2(wsu[P_EN_W1 + 32 + j1]), W.en_b1[j1])), 0.f);
      h2 hh = pkrtz(h0, h1);
#pragma unroll
      for (int d = 0; d < 16; ++d)
        self_out[d] = fdot2(hh, asH2(wsu[P_EN_W2 + jp*16 + d]), self_out[d]);
    }
#pragma unroll
    for (int d = 0; d < 16; ++d) self_out[d] = fmaxf(self_out[d], 0.f);
  }

  // ------- other agents: 15 entities = 5 passes of 3 ---------------------
  float other_pool[16];
  {
    float m = -3.0e38f, l = 0.f, acc[16];
#pragma unroll
    for (int d = 0; d < 16; ++d) acc[d] = 0.f;
#pragma unroll 1
    for (int k0 = 0; k0 < 15; k0 += 3)
      oa_batch<3>(srow, k0, W, wsu, self_out, acc, m, l);

    float inv = 1.f / l;
    float mu = 0.f;
#pragma unroll
    for (int d = 0; d < 16; ++d) { acc[d] *= inv; mu += acc[d]; }
    mu *= (1.f / 16.f);
    float var = 0.f;
#pragma unroll
    for (int d = 0; d < 16; ++d) { float x = acc[d] - mu; var = fmaf(x, x, var); }
    var *= (1.f / 16.f);
    float rstd = rsqrtf(var + LN_EPS);
#pragma unroll
    for (int d = 0; d < 16; ++d)
      other_pool[d] = fmaxf(fmaf((acc[d] - mu) * rstd, W.oa_g[d], W.oa_b[d]), 0.f);
  }

  // ------- food: 16 entities = 4 passes of 4 -----------------------------
  float food_pool[16];
  {
    float m = -3.0e38f, l = 0.f, acc[16];
#pragma unroll
    for (int d = 0; d < 16; ++d) acc[d] = 0.f;
#pragma unroll 1
    for (int k0 = 0; k0 < 16; k0 += 4)
      go_batch<4>(srow, k0, W, wsu, self_out, acc, m, l);

    float inv = 1.f / l;
    float mu = 0.f;
#pragma unroll
    for (int d = 0; d < 16; ++d) { acc[d] *= inv; mu += acc[d]; }
    mu *= (1.f / 16.f);
    float var = 0.f;
#pragma unroll
    for (int d = 0; d < 16; ++d) { float x = acc[d] - mu; var = fmaf(x, x, var); }
    var *= (1.f / 16.f);
    float rstd = rsqrtf(var + LN_EPS);
#pragma unroll
    for (int d = 0; d < 16; ++d)
      food_pool[d] = fmaxf(fmaf((acc[d] - mu) * rstd, W.go_g[d], W.go_b[d]), 0.f);
  }

  // ------- action head: 48 -> 32 -> 32 -> 2, via dot2 --------------------
  h2 mh[24];
#pragma unroll
  for (int c = 0; c < 8; ++c) mh[c]      = pkrtz(self_out[2*c],  self_out[2*c+1]);
#pragma unroll
  for (int c = 0; c < 8; ++c) mh[8 + c]  = pkrtz(food_pool[2*c], food_pool[2*c+1]);
#pragma unroll
  for (int c = 0; c < 8; ++c) mh[16 + c] = pkrtz(other_pool[2*c], other_pool[2*c+1]);

  float h1v[32];
#pragma unroll
  for (int j = 0; j < 32; ++j) h1v[j] = W.a_b1[j];
#pragma unroll
  for (int cp = 0; cp < 24; ++cp) {
    h2 v = mh[cp];
#pragma unroll
    for (int j = 0; j < 32; ++j)
      h1v[j] = fdot2(v, asH2(wsu[P_A_W1 + cp*32 + j]), h1v[j]);
  }
#pragma unroll
  for (int j = 0; j < 32; ++j) h1v[j] = fmaxf(h1v[j], 0.01f * h1v[j]);  // leaky

  h2 hh1[16];
#pragma unroll
  for (int c = 0; c < 16; ++c) hh1[c] = pkrtz(h1v[2*c], h1v[2*c+1]);

  float h2v[32];
#pragma unroll
  for (int j = 0; j < 32; ++j) h2v[j] = W.a_b2[j];
#pragma unroll
  for (int cp = 0; cp < 16; ++cp) {
    h2 v = hh1[cp];
#pragma unroll
    for (int j = 0; j < 32; ++j)
      h2v[j] = fdot2(v, asH2(wsu[P_A_W2 + cp*32 + j]), h2v[j]);
  }
#pragma unroll
  for (int j = 0; j < 32; ++j) h2v[j] = fmaxf(h2v[j], 0.01f * h2v[j]);

  h2 hh2[16];
#pragma unroll
  for (int c = 0; c < 16; ++c) hh2[c] = pkrtz(h2v[2*c], h2v[2*c+1]);

  float o0 = W.a_b3[0], o1 = W.a_b3[1];
#pragma unroll
  for (int cp = 0; cp < 16; ++cp) {
    o0 = fdot2(hh2[cp], asH2(wsu[P_A_W3 + cp*2 + 0]), o0);
    o1 = fdot2(hh2[cp], asH2(wsu[P_A_W3 + cp*2 + 1]), o1);
  }
  o0 = tanhf(o0);
  o1 = tanhf(o1);

  reinterpret_cast<float2*>(out)[row] = make_float2(o0, o1);
}

extern "C" void kernel_launch(void* const* d_in, const int* in_sizes, int n_in,
                              void* d_out, int out_size, void* d_ws, size_t ws_size,
                              hipStream_t stream) {
  const float* s_input = (const float*)d_in[0];
  Weights W;
  W.en_W1 = (const float*)d_in[1];  W.en_b1 = (const float*)d_in[2];
  W.en_W2 = (const float*)d_in[3];  W.en_b2 = (const float*)d_in[4];
  W.oa_W1 = (const float*)d_in[5];  W.oa_b1 = (const float*)d_in[6];
  W.oa_W2 = (const float*)d_in[7];  W.oa_b2 = (const float*)d_in[8];
  W.go_W1 = (const float*)d_in[9];  W.go_b1 = (const float*)d_in[10];
  W.go_W2 = (const float*)d_in[11]; W.go_b2 = (const float*)d_in[12];
  W.oa_g  = (const float*)d_in[13]; W.oa_b  = (const float*)d_in[14];
  W.go_g  = (const float*)d_in[15]; W.go_b  = (const float*)d_in[16];
  W.a_W1  = (const float*)d_in[17]; W.a_b1  = (const float*)d_in[18];
  W.a_W2  = (const float*)d_in[19]; W.a_b2  = (const float*)d_in[20];
  W.a_W3  = (const float*)d_in[21]; W.a_b3  = (const float*)d_in[22];

  uint32_t* wsu = (uint32_t*)d_ws;   // needs 8960 bytes
  prep_weights<<<1, 256, 0, stream>>>(W, wsu);

  const int bsz = in_sizes[0] / 96;          // 262144
  const int blocks = (bsz + 255) / 256;      // 256 rows per block, 4 waves
  actor_fwd<<<blocks, 256, 0, stream>>>(s_input, W, wsu, (float*)d_out, bsz);
}